// Round 1
// 952.456 us; speedup vs baseline: 1.1064x; 1.1064x over previous
//
#include <hip/hip_runtime.h>
#include <stdint.h>

// Problem dims (fixed by the reference)
#define TT 256
#define SS 256
#define FF 1024
#define AA 256

typedef __attribute__((ext_vector_type(8))) short short8;
typedef __attribute__((ext_vector_type(8))) unsigned short ushort8v;
typedef __attribute__((ext_vector_type(4))) float floatx4;

// fp32 -> bf16 round-to-nearest-even (bit manipulation; avoids header type churn)
__device__ __forceinline__ unsigned short f2bf(float f) {
  unsigned int u = __float_as_uint(f);
  u += 0x7FFFu + ((u >> 16) & 1u);
  return (unsigned short)(u >> 16);
}

// async global->LDS, 16 B per lane; LDS dest = wave-uniform base + lane*16
__device__ __forceinline__ void gl_lds16(const unsigned short* g, unsigned short* l) {
  __builtin_amdgcn_global_load_lds(
      (__attribute__((address_space(1))) void*)(g),
      (__attribute__((address_space(3))) void*)(l), 16, 0, 0);
}

// ---------------------------------------------------------------------------
// Whole-tensor fp32 -> bf16 convert (memory-bound pre-pass for batch).
// 8 elems / thread-iter: 32 B fp32 in, 16 B bf16 out, grid-stride.
// ---------------------------------------------------------------------------
__global__ __launch_bounds__(256) void k_cvt_bf16(const float* __restrict__ in,
                                                  unsigned short* __restrict__ out,
                                                  long n8) {
  long i = (long)blockIdx.x * 256 + threadIdx.x;
  const long stride = (long)gridDim.x * 256;
  for (; i < n8; i += stride) {
    const floatx4 v0 = *(const floatx4*)(in + i * 8);
    const floatx4 v1 = *(const floatx4*)(in + i * 8 + 4);
    ushort8v h;
    h[0] = f2bf(v0.x); h[1] = f2bf(v0.y); h[2] = f2bf(v0.z); h[3] = f2bf(v0.w);
    h[4] = f2bf(v1.x); h[5] = f2bf(v1.y); h[6] = f2bf(v1.z); h[7] = f2bf(v1.w);
    *(ushort8v*)(out + i * 8) = h;
  }
}

// ---------------------------------------------------------------------------
// Weight transpose + fp32->bf16:  WT[n][k] = bf16(W[k][n]).  W: K x N fp32.
// ---------------------------------------------------------------------------
__global__ void k_transpose_cvt(const float* __restrict__ W,
                                unsigned short* __restrict__ WT,
                                int K, int N) {
  __shared__ float tile[32][33];
  const int bk = blockIdx.x * 32, bn = blockIdx.y * 32;
  const int tx = threadIdx.x, ty = threadIdx.y;
  for (int i = ty; i < 32; i += 8)
    tile[i][tx] = W[(size_t)(bk + i) * N + bn + tx];
  __syncthreads();
  for (int i = ty; i < 32; i += 8)
    WT[(size_t)(bn + i) * K + bk + tx] = f2bf(tile[tx][i]);
}

// ---------------------------------------------------------------------------
// Fused projection GEMM, bf16-A variant (m97 structure, both operands via
// global_load_lds width-16; zero VALU conversion in the hot loop):
//   C = batch16(65536x1024 bf16) @ [aT|bT|gT]^T + bias
//   n-tile 0..1  -> theta  (bf16, row-major 65536x256)
//   n-tile 2..3  -> phi    (bf16, row-major 65536x256)
//   n-tile 4..11 -> featsT (bf16, TRANSPOSED store: featsT[t][f][s])
// 128x128 tile, BK=32, 4 waves, 4x4 16x16x32 MFMA frags.
// ---------------------------------------------------------------------------
__global__ __launch_bounds__(256) void k_proj_b16(
    const unsigned short* __restrict__ batch16,
    const unsigned short* __restrict__ aT,
    const unsigned short* __restrict__ bT,
    const unsigned short* __restrict__ gT,
    const float* __restrict__ a_b, const float* __restrict__ b_b,
    const float* __restrict__ g_b,
    unsigned short* __restrict__ theta,
    unsigned short* __restrict__ phi,
    unsigned short* __restrict__ featsT) {
  const int K = FF;  // 1024
  __shared__ unsigned short As[128 * 32];
  __shared__ unsigned short Bs[128 * 32];

  const int nt = blockIdx.x, mt = blockIdx.y;
  const int m0 = mt * 128;
  const unsigned short* Wt;
  const float* bias;
  int nloc0, mode;  // mode: 0 theta, 1 phi, 2 featsT
  if (nt < 2)      { Wt = aT; bias = a_b; nloc0 = nt * 128;       mode = 0; }
  else if (nt < 4) { Wt = bT; bias = b_b; nloc0 = (nt - 2) * 128; mode = 1; }
  else             { Wt = gT; bias = g_b; nloc0 = (nt - 4) * 128; mode = 2; }

  const int tid = threadIdx.x;
  const int lane = tid & 63, wave = tid >> 6;
  const int wm = wave >> 1, wn = wave & 1;
  const int lr = lane & 15, lq = lane >> 4;

  floatx4 acc[4][4];
#pragma unroll
  for (int i = 0; i < 4; i++)
#pragma unroll
    for (int j = 0; j < 4; j++) acc[i][j] = (floatx4)0.0f;

  for (int k0 = 0; k0 < K; k0 += 32) {
    __syncthreads();
    int sl = tid;
    gl_lds16(batch16 + (size_t)(m0 + (sl >> 2)) * K + k0 + (sl & 3) * 8,
             &As[wave * 512]);
    gl_lds16(Wt + (size_t)(nloc0 + (sl >> 2)) * K + k0 + (sl & 3) * 8,
             &Bs[wave * 512]);
    sl = tid + 256;
    gl_lds16(batch16 + (size_t)(m0 + (sl >> 2)) * K + k0 + (sl & 3) * 8,
             &As[2048 + wave * 512]);
    gl_lds16(Wt + (size_t)(nloc0 + (sl >> 2)) * K + k0 + (sl & 3) * 8,
             &Bs[2048 + wave * 512]);
    __syncthreads();

    short8 af[4], bfr[4];
#pragma unroll
    for (int i = 0; i < 4; i++)
      af[i] = *(const short8*)&As[(wm * 64 + i * 16 + lr) * 32 + lq * 8];
#pragma unroll
    for (int j = 0; j < 4; j++)
      bfr[j] = *(const short8*)&Bs[(wn * 64 + j * 16 + lr) * 32 + lq * 8];
#pragma unroll
    for (int i = 0; i < 4; i++)
#pragma unroll
      for (int j = 0; j < 4; j++)
        acc[i][j] = __builtin_amdgcn_mfma_f32_16x16x32_bf16(af[i], bfr[j],
                                                            acc[i][j], 0, 0, 0);
  }

  // Epilogue. C/D layout: col = lane&15, row = (lane>>4)*4 + reg.
#pragma unroll
  for (int i = 0; i < 4; i++) {
    const int row0 = wm * 64 + i * 16 + lq * 4;
#pragma unroll
    for (int j = 0; j < 4; j++) {
      const int col = wn * 64 + j * 16 + lr;
      const float bv = bias[nloc0 + col];
      if (mode == 2) {
        // featsT[t][f][s]; 4 consecutive rows (s) are contiguous -> 8B store
        const int m = m0 + row0;
        const int t = m >> 8, s = m & 255;
        ushort4 h;
        h.x = f2bf(acc[i][j][0] + bv);
        h.y = f2bf(acc[i][j][1] + bv);
        h.z = f2bf(acc[i][j][2] + bv);
        h.w = f2bf(acc[i][j][3] + bv);
        *(ushort4*)&featsT[((size_t)t * FF + nloc0 + col) * SS + s] = h;
      } else {
        unsigned short* outp = (mode == 0) ? theta : phi;
#pragma unroll
        for (int rr = 0; rr < 4; rr++)
          outp[(size_t)(m0 + row0 + rr) * AA + nloc0 + col] =
              f2bf(acc[i][j][rr] + bv);
      }
    }
  }
}

// ---------------------------------------------------------------------------
// Fused projection GEMM, fp32-A FALLBACK (previous verified kernel; used only
// if the workspace is too small for the bf16 batch copy).
// ---------------------------------------------------------------------------
__global__ __launch_bounds__(256) void k_proj(
    const float* __restrict__ batch,
    const unsigned short* __restrict__ aT,
    const unsigned short* __restrict__ bT,
    const unsigned short* __restrict__ gT,
    const float* __restrict__ a_b, const float* __restrict__ b_b,
    const float* __restrict__ g_b,
    unsigned short* __restrict__ theta,
    unsigned short* __restrict__ phi,
    unsigned short* __restrict__ featsT) {
  const int K = FF;  // 1024
  __shared__ unsigned short As[128 * 32];
  __shared__ unsigned short Bs[128 * 32];

  const int nt = blockIdx.x, mt = blockIdx.y;
  const int m0 = mt * 128;
  const unsigned short* Wt;
  const float* bias;
  int nloc0, mode;  // mode: 0 theta, 1 phi, 2 featsT
  if (nt < 2)      { Wt = aT; bias = a_b; nloc0 = nt * 128;       mode = 0; }
  else if (nt < 4) { Wt = bT; bias = b_b; nloc0 = (nt - 2) * 128; mode = 1; }
  else             { Wt = gT; bias = g_b; nloc0 = (nt - 4) * 128; mode = 2; }

  const int tid = threadIdx.x;
  const int lane = tid & 63, wave = tid >> 6;
  const int wm = wave >> 1, wn = wave & 1;
  const int lr = lane & 15, lq = lane >> 4;

  floatx4 acc[4][4];
#pragma unroll
  for (int i = 0; i < 4; i++)
#pragma unroll
    for (int j = 0; j < 4; j++) acc[i][j] = (floatx4)0.0f;

  for (int k0 = 0; k0 < K; k0 += 32) {
    __syncthreads();
    // B tile (128 n-rows x 32 k), bf16, async DMA. slot = 16B = 8 elems.
    {
      int sl = tid;
      gl_lds16(Wt + (size_t)(nloc0 + (sl >> 2)) * K + k0 + (sl & 3) * 8,
               &Bs[wave * 512]);
      sl = tid + 256;
      gl_lds16(Wt + (size_t)(nloc0 + (sl >> 2)) * K + k0 + (sl & 3) * 8,
               &Bs[2048 + wave * 512]);
    }
    // A tile (128 m-rows x 32 k) fp32 -> bf16 manual staging
#pragma unroll
    for (int sgi = 0; sgi < 4; sgi++) {
      int g = sgi * 256 + tid;
      int row = g >> 3, c4 = g & 7;
      const floatx4 v =
          *(const floatx4*)(batch + (size_t)(m0 + row) * K + k0 + c4 * 4);
      ushort4 h;
      h.x = f2bf(v.x); h.y = f2bf(v.y); h.z = f2bf(v.z); h.w = f2bf(v.w);
      *(ushort4*)&As[row * 32 + c4 * 4] = h;
    }
    __syncthreads();

    short8 af[4], bfr[4];
#pragma unroll
    for (int i = 0; i < 4; i++)
      af[i] = *(const short8*)&As[(wm * 64 + i * 16 + lr) * 32 + lq * 8];
#pragma unroll
    for (int j = 0; j < 4; j++)
      bfr[j] = *(const short8*)&Bs[(wn * 64 + j * 16 + lr) * 32 + lq * 8];
#pragma unroll
    for (int i = 0; i < 4; i++)
#pragma unroll
      for (int j = 0; j < 4; j++)
        acc[i][j] = __builtin_amdgcn_mfma_f32_16x16x32_bf16(af[i], bfr[j],
                                                            acc[i][j], 0, 0, 0);
  }

  // Epilogue. C/D layout: col = lane&15, row = (lane>>4)*4 + reg.
#pragma unroll
  for (int i = 0; i < 4; i++) {
    const int row0 = wm * 64 + i * 16 + lq * 4;
#pragma unroll
    for (int j = 0; j < 4; j++) {
      const int col = wn * 64 + j * 16 + lr;
      const float bv = bias[nloc0 + col];
      if (mode == 2) {
        const int m = m0 + row0;
        const int t = m >> 8, s = m & 255;
        ushort4 h;
        h.x = f2bf(acc[i][j][0] + bv);
        h.y = f2bf(acc[i][j][1] + bv);
        h.z = f2bf(acc[i][j][2] + bv);
        h.w = f2bf(acc[i][j][3] + bv);
        *(ushort4*)&featsT[((size_t)t * FF + nloc0 + col) * SS + s] = h;
      } else {
        unsigned short* outp = (mode == 0) ? theta : phi;
#pragma unroll
        for (int rr = 0; rr < 4; rr++)
          outp[(size_t)(m0 + row0 + rr) * AA + nloc0 + col] =
              f2bf(acc[i][j][rr] + bv);
      }
    }
  }
}

// ---------------------------------------------------------------------------
// Generic batched bt-GEMM (bf16 in): C[m][n] = scale * sum_k A[m][k]*B[n][k]
// A: M x K row-major (ld=K), B: N x K row-major (ld=K), batched over grid.z.
// ---------------------------------------------------------------------------
template <bool OUTF32>
__global__ __launch_bounds__(256) void k_gemm_bt(
    const unsigned short* __restrict__ A, const unsigned short* __restrict__ B,
    void* __restrict__ C, int N, int K, long sA, long sB, long sC,
    float scale) {
  __shared__ unsigned short As[128 * 32];
  __shared__ unsigned short Bs[128 * 32];
  const unsigned short* Ab = A + (size_t)blockIdx.z * sA;
  const unsigned short* Bb = B + (size_t)blockIdx.z * sB;
  const int n0 = blockIdx.x * 128, m0 = blockIdx.y * 128;
  const int tid = threadIdx.x, lane = tid & 63, wave = tid >> 6;
  const int wm = wave >> 1, wn = wave & 1, lr = lane & 15, lq = lane >> 4;

  floatx4 acc[4][4];
#pragma unroll
  for (int i = 0; i < 4; i++)
#pragma unroll
    for (int j = 0; j < 4; j++) acc[i][j] = (floatx4)0.0f;

  for (int k0 = 0; k0 < K; k0 += 32) {
    __syncthreads();
    int sl = tid;
    gl_lds16(Ab + (size_t)(m0 + (sl >> 2)) * K + k0 + (sl & 3) * 8,
             &As[wave * 512]);
    gl_lds16(Bb + (size_t)(n0 + (sl >> 2)) * K + k0 + (sl & 3) * 8,
             &Bs[wave * 512]);
    sl = tid + 256;
    gl_lds16(Ab + (size_t)(m0 + (sl >> 2)) * K + k0 + (sl & 3) * 8,
             &As[2048 + wave * 512]);
    gl_lds16(Bb + (size_t)(n0 + (sl >> 2)) * K + k0 + (sl & 3) * 8,
             &Bs[2048 + wave * 512]);
    __syncthreads();

    short8 af[4], bfr[4];
#pragma unroll
    for (int i = 0; i < 4; i++)
      af[i] = *(const short8*)&As[(wm * 64 + i * 16 + lr) * 32 + lq * 8];
#pragma unroll
    for (int j = 0; j < 4; j++)
      bfr[j] = *(const short8*)&Bs[(wn * 64 + j * 16 + lr) * 32 + lq * 8];
#pragma unroll
    for (int i = 0; i < 4; i++)
#pragma unroll
      for (int j = 0; j < 4; j++)
        acc[i][j] = __builtin_amdgcn_mfma_f32_16x16x32_bf16(af[i], bfr[j],
                                                            acc[i][j], 0, 0, 0);
  }

#pragma unroll
  for (int i = 0; i < 4; i++) {
    const int row0 = wm * 64 + i * 16 + lq * 4;
#pragma unroll
    for (int j = 0; j < 4; j++) {
      const int col = wn * 64 + j * 16 + lr;
#pragma unroll
      for (int rr = 0; rr < 4; rr++) {
        const float v = acc[i][j][rr] * scale;
        if (OUTF32) {
          float* Cb = (float*)C + (size_t)blockIdx.z * sC;
          Cb[(size_t)(m0 + row0 + rr) * N + n0 + col] = v;
        } else {
          unsigned short* Cb = (unsigned short*)C + (size_t)blockIdx.z * sC;
          Cb[(size_t)(m0 + row0 + rr) * N + n0 + col] = f2bf(v);
        }
      }
    }
  }
}

// ---------------------------------------------------------------------------
extern "C" void kernel_launch(void* const* d_in, const int* in_sizes, int n_in,
                              void* d_out, int out_size, void* d_ws,
                              size_t ws_size, hipStream_t stream) {
  const float* batch = (const float*)d_in[0];
  const float* a_w   = (const float*)d_in[1];
  const float* a_b   = (const float*)d_in[2];
  const float* b_w   = (const float*)d_in[3];
  const float* b_b   = (const float*)d_in[4];
  const float* g_w   = (const float*)d_in[5];
  const float* g_b   = (const float*)d_in[6];
  float* out = (float*)d_out;

  // Workspace layout (bf16 elements).
  // Base = 238,026,752 B; +batch16 (134,217,728 B) => 372,244,480 B total.
  unsigned short* ws     = (unsigned short*)d_ws;
  unsigned short* aT     = ws;                                   // 256x1024
  unsigned short* bT     = aT + (size_t)AA * FF;                 // 256x1024
  unsigned short* gT     = bT + (size_t)AA * FF;                 // 1024x1024
  unsigned short* theta  = gT + (size_t)FF * FF;                 // 65536x256
  unsigned short* phi    = theta + (size_t)TT * SS * AA;         // 65536x256
  unsigned short* featsT = phi + (size_t)TT * SS * AA;           // [t][f][s]
  unsigned short* attn   = featsT + (size_t)TT * FF * SS;        // [t][s][r]
  unsigned short* batch16 = attn + (size_t)TT * SS * SS;         // 65536x1024

  const size_t need_b16 =
      ((size_t)2 * AA * FF + (size_t)FF * FF + (size_t)2 * TT * SS * AA +
       (size_t)TT * FF * SS + (size_t)TT * SS * SS + (size_t)TT * SS * FF) *
      sizeof(unsigned short);

  dim3 tb(32, 8);
  k_transpose_cvt<<<dim3(32, 8),  tb, 0, stream>>>(a_w, aT, FF, AA);
  k_transpose_cvt<<<dim3(32, 8),  tb, 0, stream>>>(b_w, bT, FF, AA);
  k_transpose_cvt<<<dim3(32, 32), tb, 0, stream>>>(g_w, gT, FF, FF);

  if (ws_size >= need_b16) {
    // One-shot batch fp32->bf16 (memory-bound), then pure-DMA projection GEMM.
    k_cvt_bf16<<<2048, 256, 0, stream>>>(batch, batch16,
                                         (long)TT * SS * FF / 8);
    k_proj_b16<<<dim3(12, 512), 256, 0, stream>>>(batch16, aT, bT, gT, a_b,
                                                  b_b, g_b, theta, phi,
                                                  featsT);
  } else {
    // Fallback: fp32 in-kernel staging (previous verified path).
    k_proj<<<dim3(12, 512), 256, 0, stream>>>(batch, aT, bT, gT, a_b, b_b,
                                              g_b, theta, phi, featsT);
  }

  // attn[t] = theta[t] @ phi[t]^T   (M=N=K=256, batched over t)
  k_gemm_bt<false><<<dim3(2, 2, TT), 256, 0, stream>>>(
      theta, phi, attn, SS, AA, (long)SS * AA, (long)SS * AA, (long)SS * SS,
      1.0f);

  // out[t] = (attn[t] @ featsT[t]^T) / 512   (M=256, N=1024, K=256)
  k_gemm_bt<true><<<dim3(8, 2, TT), 256, 0, stream>>>(
      attn, featsT, out, FF, SS, (long)SS * SS, (long)FF * SS, (long)SS * FF,
      1.0f / 512.0f);
}